// Round 9
// baseline (607.075 us; speedup 1.0000x reference)
//
#include <hip/hip_runtime.h>
#include <math.h>

typedef unsigned short u16;
typedef short short8 __attribute__((ext_vector_type(8)));
typedef float f32x4 __attribute__((ext_vector_type(4)));

#define Bc 4
#define Nc_ 4096
#define DINc 768
#define Dc 256
#define Sc 8
#define SCALEc 0.0625f
#define EPSc 1e-8f

__device__ __forceinline__ u16 f2bf(float f) {
    union { float f; unsigned u; } x; x.f = f;
    unsigned r = x.u + 0x7fffu + ((x.u >> 16) & 1u);
    return (u16)(r >> 16);
}
__device__ __forceinline__ float bf2f(u16 v) {
    union { unsigned u; float f; } x; x.u = ((unsigned)v) << 16; return x.f;
}
__device__ __forceinline__ float rfl(float x) {
    return __int_as_float(__builtin_amdgcn_readfirstlane(__float_as_int(x)));
}

#define GLDS(g, l) __builtin_amdgcn_global_load_lds( \
    (const __attribute__((address_space(1))) void*)(g), \
    (__attribute__((address_space(3))) void*)(l), 16, 0, 0)

// ================= bf16 MFMA GEMM: C[M][N] = A[M][K] @ Bt[N][K]^T + bias ================
template<bool RELU, bool BF16OUT>
__global__ __launch_bounds__(256) void mfma_gemm(
    const u16* __restrict__ A, const u16* __restrict__ Bt,
    const float* __restrict__ bias, void* __restrict__ Cv,
    int M, int N, int K)
{
    __shared__ u16 lA[128 * 32];
    __shared__ u16 lB[128 * 32];
    const int tid = threadIdx.x;
    const int lane = tid & 63, w = tid >> 6;
    const int wm = w >> 1, wn = w & 1;
    const int m0 = blockIdx.y * 128, n0 = blockIdx.x * 128;

    f32x4 acc[4][4];
    #pragma unroll
    for (int mi = 0; mi < 4; mi++)
        #pragma unroll
        for (int ni = 0; ni < 4; ni++)
            #pragma unroll
            for (int r = 0; r < 4; r++) acc[mi][ni][r] = 0.f;

    const int arow = (w << 5) + (lane >> 2);
    const int kc_s = (((lane & 3) ^ ((arow >> 1) & 3)) << 3);
    const size_t K16 = (size_t)K << 4;
    const u16* ga = A + (size_t)(m0 + arow) * K + kc_s;
    const u16* gb = Bt + (size_t)(n0 + arow) * K + kc_s;
    u16* la0 = &lA[w << 10];
    u16* la1 = &lA[(w << 10) + 512];
    u16* lb0 = &lB[w << 10];
    u16* lb1 = &lB[(w << 10) + 512];

    for (int k0 = 0; k0 < K; k0 += 32) {
        GLDS(ga + k0, la0);
        GLDS(ga + k0 + K16, la1);
        GLDS(gb + k0, lb0);
        GLDS(gb + k0 + K16, lb1);
        asm volatile("s_waitcnt vmcnt(0)" ::: "memory");
        __syncthreads();
        short8 af[4], bf[4];
        #pragma unroll
        for (int mi = 0; mi < 4; mi++) {
            int row = (wm << 6) + (mi << 4) + (lane & 15);
            int koff = (((lane >> 4) ^ ((row >> 1) & 3)) << 3);
            af[mi] = *(const short8*)&lA[row * 32 + koff];
        }
        #pragma unroll
        for (int ni = 0; ni < 4; ni++) {
            int row = (wn << 6) + (ni << 4) + (lane & 15);
            int koff = (((lane >> 4) ^ ((row >> 1) & 3)) << 3);
            bf[ni] = *(const short8*)&lB[row * 32 + koff];
        }
        #pragma unroll
        for (int mi = 0; mi < 4; mi++)
            #pragma unroll
            for (int ni = 0; ni < 4; ni++)
                acc[mi][ni] = __builtin_amdgcn_mfma_f32_16x16x32_bf16(af[mi], bf[ni], acc[mi][ni], 0, 0, 0);
        __syncthreads();
    }

    const int ccol = lane & 15;
    const int crow = (lane >> 4) << 2;
    #pragma unroll
    for (int mi = 0; mi < 4; mi++) {
        #pragma unroll
        for (int ni = 0; ni < 4; ni++) {
            int colg = n0 + (wn << 6) + (ni << 4) + ccol;
            float bv = bias ? bias[colg] : 0.f;
            #pragma unroll
            for (int r = 0; r < 4; r++) {
                int rowg = m0 + (wm << 6) + (mi << 4) + crow + r;
                float v = acc[mi][ni][r] + bv;
                if (RELU) v = fmaxf(v, 0.f);
                if (BF16OUT) ((u16*)Cv)[(size_t)rowg * N + colg] = f2bf(v);
                else         ((float*)Cv)[(size_t)rowg * N + colg] = v;
            }
        }
    }
}

// ============== row-LayerNorm + bf16 convert, f32 input (K<=768) ==============
__global__ __launch_bounds__(256) void lncvt_k(
    const float* __restrict__ X, const float* __restrict__ g, const float* __restrict__ b,
    u16* __restrict__ out, int K)
{
    int row = blockIdx.x, tid = threadIdx.x, lane = tid & 63, wave = tid >> 6;
    __shared__ float buf[768];
    __shared__ float rs[4], rs2[4];
    float s = 0.f, s2 = 0.f;
    for (int k = tid; k < K; k += 256) {
        float v = X[(size_t)row * K + k];
        buf[k] = v; s += v; s2 += v * v;
    }
    #pragma unroll
    for (int off = 32; off > 0; off >>= 1) { s += __shfl_xor(s, off); s2 += __shfl_xor(s2, off); }
    if (lane == 0) { rs[wave] = s; rs2[wave] = s2; }
    __syncthreads();
    float inv = 1.f / (float)K;
    float mean = (rs[0] + rs[1] + rs[2] + rs[3]) * inv;
    float m2 = (rs2[0] + rs2[1] + rs2[2] + rs2[3]) * inv;
    float rstd = rsqrtf(m2 - mean * mean + 1e-5f);
    for (int k = tid; k < K; k += 256)
        out[(size_t)row * K + k] = f2bf((buf[k] - mean) * rstd * g[k] + b[k]);
}

// ============== row-LayerNorm in-place on bf16 (K==256) ==============
__global__ __launch_bounds__(256) void lncvt_bf_k(
    u16* __restrict__ X, const float* __restrict__ g, const float* __restrict__ b)
{
    int row = blockIdx.x, tid = threadIdx.x, lane = tid & 63, wave = tid >> 6;
    __shared__ float rs[4], rs2[4];
    float v = bf2f(X[(size_t)row * 256 + tid]);
    float s = v, s2 = v * v;
    #pragma unroll
    for (int off = 32; off > 0; off >>= 1) { s += __shfl_xor(s, off); s2 += __shfl_xor(s2, off); }
    if (lane == 0) { rs[wave] = s; rs2[wave] = s2; }
    __syncthreads();
    float mean = (rs[0] + rs[1] + rs[2] + rs[3]) * (1.f / 256.f);
    float m2 = (rs2[0] + rs2[1] + rs2[2] + rs2[3]) * (1.f / 256.f);
    float rstd = rsqrtf(m2 - mean * mean + 1e-5f);
    X[(size_t)row * 256 + tid] = f2bf((v - mean) * rstd * g[tid] + b[tid]);
}

// ============== merged 3-way transpose+convert (f32 -> bf16 transposed) ==============
__global__ __launch_bounds__(256) void tcvt3_k(
    const float* __restrict__ in0, u16* __restrict__ out0,
    const float* __restrict__ in1, u16* __restrict__ out1,
    const float* __restrict__ in2, u16* __restrict__ out2)
{
    int z = blockIdx.z;
    const float* in; u16* out; int R, C;
    if (z == 0) { in = in0; out = out0; R = 768; C = 768; }
    else if (z == 1) { in = in1; out = out1; R = 768; C = 256; }
    else { in = in2; out = out2; R = 256; C = 512; }
    int r0 = blockIdx.y * 32, c0 = blockIdx.x * 32;
    if (r0 >= R || c0 >= C) return;
    __shared__ float tile[32][33];
    int tx = threadIdx.x & 31, ty = threadIdx.x >> 5;
    #pragma unroll
    for (int i = 0; i < 32; i += 8)
        tile[ty + i][tx] = in[(size_t)(r0 + ty + i) * C + c0 + tx];
    __syncthreads();
    #pragma unroll
    for (int i = 0; i < 32; i += 8)
        out[(size_t)(c0 + ty + i) * R + r0 + tx] = f2bf(tile[tx][ty + i]);
}

// ============== merged 5-way f32 transpose (for coalesced column-matvec weights) ========
__global__ __launch_bounds__(256) void tcvtf_k(
    const float* __restrict__ fw2, float* __restrict__ fw2t,   // 256x256
    const float* __restrict__ wi,  float* __restrict__ wit,    // 256x768
    const float* __restrict__ wh,  float* __restrict__ wht,    // 256x768
    const float* __restrict__ w1,  float* __restrict__ w1t,    // 256x1024
    const float* __restrict__ w2,  float* __restrict__ w2t)    // 1024x256
{
    int z = blockIdx.z;
    const float* in; float* out; int R, C;
    if (z == 0)      { in = fw2; out = fw2t; R = 256;  C = 256; }
    else if (z == 1) { in = wi;  out = wit;  R = 256;  C = 768; }
    else if (z == 2) { in = wh;  out = wht;  R = 256;  C = 768; }
    else if (z == 3) { in = w1;  out = w1t;  R = 256;  C = 1024; }
    else             { in = w2;  out = w2t;  R = 1024; C = 256; }
    int r0 = blockIdx.y * 32, c0 = blockIdx.x * 32;
    if (r0 >= R || c0 >= C) return;
    __shared__ float tile[32][33];
    int tx = threadIdx.x & 31, ty = threadIdx.x >> 5;
    #pragma unroll
    for (int i = 0; i < 32; i += 8)
        tile[ty + i][tx] = in[(size_t)(r0 + ty + i) * C + c0 + tx];
    __syncthreads();
    #pragma unroll
    for (int i = 0; i < 32; i += 8)
        out[(size_t)(c0 + ty + i) * R + r0 + tx] = tile[tx][ty + i];
}

// ============ merged one-time precompute ====
__global__ __launch_bounds__(512) void prep_k(
    const float* __restrict__ Kw, const float* __restrict__ Vw, const float* __restrict__ fw1,
    const float* __restrict__ gw, const float* __restrict__ gb, const float* __restrict__ fb1,
    const float* __restrict__ Qw, const float* __restrict__ fb2, const float* __restrict__ fw2,
    const float* __restrict__ slots_param, const float* __restrict__ Sp0, const float* __restrict__ Ss0,
    float* __restrict__ KVF, float* __restrict__ G3, float* __restrict__ bias2,
    float* __restrict__ qv, float* __restrict__ slots, float* __restrict__ Spb, float* __restrict__ Ssb,
    u16* __restrict__ Qwbf, u16* __restrict__ fw2bf)
{
    int blk = blockIdx.x, tid = threadIdx.x;
    if (blk < 256) {
        int k = blk, j = tid;
        const float* Mrow = (j < 256 ? Kw : Vw) + k * 256;
        int jj = j & 255;
        float acc = 0.f;
        for (int d = 0; d < 256; d++) acc += Mrow[d] * fw1[d * 256 + jj];
        KVF[k * 512 + j] = acc;
    } else if (blk == 256) {
        if (tid < 256) {
            int j = tid;
            float g0 = 0, g1 = 0, g2 = 0, bb = 0;
            for (int d = 0; d < 256; d++) {
                float f = fw1[d * 256 + j];
                g0 += gw[d] * f; g1 += gw[256 + d] * f; g2 += gw[512 + d] * f;
                bb += gb[d] * f;
            }
            G3[j] = g0; G3[256 + j] = g1; G3[512 + j] = g2;
            float b1v = fb1[j] + bb;
            bias2[j] = b1v; bias2[256 + j] = b1v;
        }
    } else if (blk == 257) {
        if (tid < 256) {
            float a = 0.f;
            for (int d = 0; d < 256; d++) a += Qw[tid * 256 + d] * fb2[d];
            qv[tid] = a;
        }
    } else if (blk < 274) {
        int idx = (blk - 258) * 512 + tid;
        slots[idx] = slots_param[idx & 2047];
        if (idx < Bc * Sc * 3) {
            int s3 = idx % 24;
            Spb[idx] = Sp0[s3];
            Ssb[idx] = Ss0[s3];
        }
    } else if (blk < 402) {
        int i = (blk - 274) * 512 + tid;
        Qwbf[i] = f2bf(Qw[i]);
    } else {
        int i = (blk - 402) * 512 + tid;
        fw2bf[i] = f2bf(fw2[i]);
    }
}

// ------- qprep: w2q = LN(slots)@QF ; qc ; invv ; zero accumulators for next iter -------
__global__ __launch_bounds__(256) void qprep2_k(
    const float* __restrict__ slots, const float* __restrict__ norm_g, const float* __restrict__ norm_b,
    const float* __restrict__ QF, const float* __restrict__ qv, const float* __restrict__ Ssb,
    float* __restrict__ w2q, float* __restrict__ qc, float* __restrict__ invv,
    float* __restrict__ denom, float* __restrict__ u1acc,
    float* __restrict__ Spacc, float* __restrict__ Epacc)
{
    int bs = blockIdx.x, tid = threadIdx.x, lane = tid & 63, wave = tid >> 6;
    __shared__ float sl[256];
    __shared__ float redS[4], redS2[4];
    u1acc[bs * 256 + tid] = 0.f;
    if (tid < 3) { Spacc[bs * 3 + tid] = 0.f; Epacc[bs * 3 + tid] = 0.f; }
    if (tid == 0) denom[bs] = 0.f;
    float v = slots[bs * 256 + tid];
    float s = v, s2 = v * v;
    #pragma unroll
    for (int off = 32; off > 0; off >>= 1) { s += __shfl_xor(s, off); s2 += __shfl_xor(s2, off); }
    if (lane == 0) { redS[wave] = s; redS2[wave] = s2; }
    __syncthreads();
    float mean = (redS[0] + redS[1] + redS[2] + redS[3]) * (1.f / 256.f);
    float m2 = (redS2[0] + redS2[1] + redS2[2] + redS2[3]) * (1.f / 256.f);
    float rstd = rsqrtf(m2 - mean * mean + 1e-5f);
    float slv = (v - mean) * rstd * norm_g[tid] + norm_b[tid];
    sl[tid] = slv;
    __syncthreads();
    float wq = 0.f;
    #pragma unroll 8
    for (int i = 0; i < 256; i++) wq += sl[i] * QF[i * 256 + tid];
    w2q[bs * 256 + tid] = wq;
    float c = slv * qv[tid];
    #pragma unroll
    for (int off = 32; off > 0; off >>= 1) c += __shfl_xor(c, off);
    __syncthreads();
    if (lane == 0) redS[wave] = c;
    __syncthreads();
    if (tid == 0) qc[bs] = redS[0] + redS[1] + redS[2] + redS[3];
    if (tid < 3) invv[bs * 3 + tid] = 1.f / (Ssb[bs * 3 + tid] * 5.0f + EPSc);
}

// ===== fused iteration: dots + softmax(s) + raw-weighted u1/moments/denom (bf16 AKV) ====
template<bool LAST>
__global__ __launch_bounds__(512, 2) void fused_iter_k(
    const u16* __restrict__ AKV, const float* __restrict__ P,
    const float* __restrict__ G3, const float* __restrict__ w2q,
    const float* __restrict__ qc, const float* __restrict__ Spb,
    const float* __restrict__ invv, float* __restrict__ denom,
    float* __restrict__ u1acc, float* __restrict__ Spacc, float* __restrict__ Epacc,
    float* __restrict__ attn_raw)
{
    const int b = blockIdx.y;
    const int tid = threadIdx.x, wave = tid >> 6, lane = tid & 63;
    __shared__ float uls[8][2048];
    __shared__ float dls[8][8];
    __shared__ float mls[8][8][6];

    const float4* G3f = (const float4*)G3;
    float4 g0 = G3f[lane], g1 = G3f[64 + lane], g2 = G3f[128 + lane];
    float4 wq[8];
    float sp0[8], sp1[8], sp2[8], iv0[8], iv1[8], iv2[8], qcr[8];
    #pragma unroll
    for (int s = 0; s < 8; s++) {
        wq[s] = ((const float4*)(w2q + (size_t)(b * 8 + s) * 256))[lane];
        sp0[s] = rfl(Spb[(b * 8 + s) * 3 + 0]);
        sp1[s] = rfl(Spb[(b * 8 + s) * 3 + 1]);
        sp2[s] = rfl(Spb[(b * 8 + s) * 3 + 2]);
        iv0[s] = rfl(invv[(b * 8 + s) * 3 + 0]);
        iv1[s] = rfl(invv[(b * 8 + s) * 3 + 1]);
        iv2[s] = rfl(invv[(b * 8 + s) * 3 + 2]);
        qcr[s] = rfl(qc[b * 8 + s]);
    }
    float4 au[8];
    #pragma unroll
    for (int s = 0; s < 8; s++) { au[s].x = 0.f; au[s].y = 0.f; au[s].z = 0.f; au[s].w = 0.f; }
    float den[8] = {0.f, 0.f, 0.f, 0.f, 0.f, 0.f, 0.f, 0.f};
    float asp0 = 0.f, asp1 = 0.f, asp2 = 0.f, aep0 = 0.f, aep1 = 0.f, aep2 = 0.f;
    float attv = 0.f;

    const int n0 = blockIdx.x * 32 + wave * 4;
    for (int i = 0; i < 4; i++) {
        size_t base = (size_t)b * Nc_ + (n0 + i);
        ushort4 akr = ((const ushort4*)(AKV + base * 512))[lane];
        float4 ak;
        ak.x = bf2f(akr.x); ak.y = bf2f(akr.y); ak.z = bf2f(akr.z); ak.w = bf2f(akr.w);
        const float* pp = P + base * 3;
        float p0 = pp[0], p1 = pp[1], p2 = pp[2];
        float a[8];
        #pragma unroll
        for (int s = 0; s < 8; s++) {
            float r0 = (p0 - sp0[s]) * iv0[s];
            float r1 = (p1 - sp1[s]) * iv1[s];
            float r2 = (p2 - sp2[s]) * iv2[s];
            float d0;
            d0  = fmaxf(ak.x + r0 * g0.x + r1 * g1.x + r2 * g2.x, 0.f) * wq[s].x;
            d0 += fmaxf(ak.y + r0 * g0.y + r1 * g1.y + r2 * g2.y, 0.f) * wq[s].y;
            d0 += fmaxf(ak.z + r0 * g0.z + r1 * g1.z + r2 * g2.z, 0.f) * wq[s].z;
            d0 += fmaxf(ak.w + r0 * g0.w + r1 * g1.w + r2 * g2.w, 0.f) * wq[s].w;
            #pragma unroll
            for (int off = 32; off > 0; off >>= 1) d0 += __shfl_xor(d0, off);
            a[s] = (d0 + qcr[s]) * SCALEc;
        }
        float mx = a[0];
        #pragma unroll
        for (int s = 1; s < 8; s++) mx = fmaxf(mx, a[s]);
        float sum = 0.f;
        #pragma unroll
        for (int s = 0; s < 8; s++) { a[s] = __expf(a[s] - mx); sum += a[s]; }
        float inv = 1.f / sum;
        #pragma unroll
        for (int s = 0; s < 8; s++) { a[s] = a[s] * inv + EPSc; den[s] += a[s]; }
        if (LAST) {
            #pragma unroll
            for (int s = 0; s < 8; s++)
                if (lane < 32 && (lane & 3) == i && (lane >> 2) == s) attv = a[s];
        } else {
            ushort4 avr = ((const ushort4*)(AKV + base * 512 + 256))[lane];
            float4 av;
            av.x = bf2f(avr.x); av.y = bf2f(avr.y); av.z = bf2f(avr.z); av.w = bf2f(avr.w);
            #pragma unroll
            for (int s = 0; s < 8; s++) {
                float r0 = (p0 - sp0[s]) * iv0[s];
                float r1 = (p1 - sp1[s]) * iv1[s];
                float r2 = (p2 - sp2[s]) * iv2[s];
                float as = a[s];
                au[s].x += as * fmaxf(av.x + r0 * g0.x + r1 * g1.x + r2 * g2.x, 0.f);
                au[s].y += as * fmaxf(av.y + r0 * g0.y + r1 * g1.y + r2 * g2.y, 0.f);
                au[s].z += as * fmaxf(av.z + r0 * g0.z + r1 * g1.z + r2 * g2.z, 0.f);
                au[s].w += as * fmaxf(av.w + r0 * g0.w + r1 * g1.w + r2 * g2.w, 0.f);
            }
            if (lane < 8) {
                float as = a[lane];
                asp0 += as * p0; asp1 += as * p1; asp2 += as * p2;
                aep0 += as * p0 * p0; aep1 += as * p1 * p1; aep2 += as * p2 * p2;
            }
        }
    }
    if (!LAST) {
        #pragma unroll
        for (int s = 0; s < 8; s++)
            *(float4*)&uls[wave][s * 256 + lane * 4] = au[s];
        if (lane < 8) {
            mls[wave][lane][0] = asp0; mls[wave][lane][1] = asp1; mls[wave][lane][2] = asp2;
            mls[wave][lane][3] = aep0; mls[wave][lane][4] = aep1; mls[wave][lane][5] = aep2;
        }
    }
    if (lane == 0) {
        #pragma unroll
        for (int s = 0; s < 8; s++) dls[wave][s] = den[s];
    }
    __syncthreads();
    if (!LAST) {
        for (int idx = tid; idx < 2048; idx += 512) {
            float v = 0.f;
            #pragma unroll
            for (int w2 = 0; w2 < 8; w2++) v += uls[w2][idx];
            atomicAdd(&u1acc[b * 2048 + idx], v);
        }
        if (tid < 48) {
            int s = tid / 6, c = tid % 6;
            float v = 0.f;
            #pragma unroll
            for (int w2 = 0; w2 < 8; w2++) v += mls[w2][s][c];
            if (c < 3) atomicAdd(&Spacc[b * 24 + s * 3 + c], v);
            else       atomicAdd(&Epacc[b * 24 + s * 3 + (c - 3)], v);
        }
    }
    if (tid < 8) {
        float v = 0.f;
        #pragma unroll
        for (int w2 = 0; w2 < 8; w2++) v += dls[w2][tid];
        atomicAdd(&denom[b * 8 + tid], v);
    }
    if (LAST && lane < 32) {
        attn_raw[(size_t)(b * 8 + (lane >> 2)) * Nc_ + n0 + (lane & 3)] = attv;
    }
}

// ===== column-parallel slot-update chain =====
// k_upd2: upd = (u1/denom)@fw2 + fb2 ; Sp/Ss finalize (block 0). grid 64 x 256.
__global__ __launch_bounds__(256) void k_upd2(
    const float* __restrict__ u1acc, const float* __restrict__ denom,
    const float* __restrict__ fw2t, const float* __restrict__ fb2,
    const float* __restrict__ Spacc, const float* __restrict__ Epacc,
    float* __restrict__ upd, float* __restrict__ Spb, float* __restrict__ Ssb)
{
    int tid = threadIdx.x, lane = tid & 63, w = tid >> 6;
    __shared__ float xu[8192];
    __shared__ float idn[32];
    if (tid < 32) idn[tid] = 1.f / denom[tid];
    __syncthreads();
    #pragma unroll 4
    for (int i = 0; i < 32; i++) xu[i * 256 + tid] = u1acc[i * 256 + tid] * idn[i];
    if (blockIdx.x == 0 && tid < 96) {
        int bs = tid / 3;
        float spv = Spacc[tid] * idn[bs];
        float ep  = Epacc[tid] * idn[bs];
        Spb[tid] = spv;
        Ssb[tid] = sqrtf(fmaxf(ep - spv * spv, 0.f) + EPSc);
    }
    __syncthreads();
    int c = blockIdx.x * 4 + w;
    const float* wr = fw2t + (size_t)c * 256;
    float wf0 = wr[lane], wf1 = wr[lane + 64], wf2 = wr[lane + 128], wf3 = wr[lane + 192];
    float bb = fb2[c];
    for (int bs = 0; bs < 32; bs++) {
        const float* x = &xu[bs * 256];
        float s = x[lane] * wf0 + x[lane + 64] * wf1 + x[lane + 128] * wf2 + x[lane + 192] * wf3;
        #pragma unroll
        for (int off = 32; off > 0; off >>= 1) s += __shfl_xor(s, off);
        if (lane == 0) upd[bs * 256 + c] = s + bb;
    }
}

// k_gates2: h[:,j] via 6 waves = {wi,wh} x {r,z,n} columns. grid 256 x 384.
__global__ __launch_bounds__(384) void k_gates2(
    const float* __restrict__ upd, const float* __restrict__ slots,
    const float* __restrict__ wit, const float* __restrict__ wht,
    const float* __restrict__ gbi, const float* __restrict__ gbh,
    float* __restrict__ hbuf)
{
    int tid = threadIdx.x, lane = tid & 63, w = tid >> 6;   // w in 0..5
    int j = blockIdx.x;
    __shared__ float xu[8192], xs[8192];
    __shared__ float part[6][32];
    for (int i = tid; i < 8192; i += 384) { xu[i] = upd[i]; xs[i] = slots[i]; }
    __syncthreads();
    int mat = w & 1, g = w >> 1;
    const float* wr = (mat ? wht : wit) + (size_t)(j + 256 * g) * 256;
    float wf0 = wr[lane], wf1 = wr[lane + 64], wf2 = wr[lane + 128], wf3 = wr[lane + 192];
    const float* xb = mat ? xs : xu;
    for (int bs = 0; bs < 32; bs++) {
        const float* x = &xb[bs * 256];
        float s = x[lane] * wf0 + x[lane + 64] * wf1 + x[lane + 128] * wf2 + x[lane + 192] * wf3;
        #pragma unroll
        for (int off = 32; off > 0; off >>= 1) s += __shfl_xor(s, off);
        if (lane == 0) part[w][bs] = s;
    }
    __syncthreads();
    if (tid < 32) {
        int bs = tid;
        float gx0 = part[0][bs] + gbi[j],       gh0 = part[1][bs] + gbh[j];
        float gx1 = part[2][bs] + gbi[j + 256], gh1 = part[3][bs] + gbh[j + 256];
        float gx2 = part[4][bs] + gbi[j + 512], gh2 = part[5][bs] + gbh[j + 512];
        float rg = 1.f / (1.f + expf(-(gx0 + gh0)));
        float zg = 1.f / (1.f + expf(-(gx1 + gh1)));
        float ng = tanhf(gx2 + rg * gh2);
        hbuf[bs * 256 + j] = (1.f - zg) * ng + zg * xs[bs * 256 + j];
    }
}

// k_mlp12: t1 = relu(LN(h)@w1 + b1). grid 256 x 256.
__global__ __launch_bounds__(256) void k_mlp12(
    const float* __restrict__ hbuf, const float* __restrict__ lng, const float* __restrict__ lnb,
    const float* __restrict__ w1t, const float* __restrict__ b1, float* __restrict__ t1)
{
    int tid = threadIdx.x, lane = tid & 63, w = tid >> 6;
    __shared__ float y0[8192];
    __shared__ float mstat[32][2];
    #pragma unroll 4
    for (int i = 0; i < 32; i++) y0[i * 256 + tid] = hbuf[i * 256 + tid];
    __syncthreads();
    #pragma unroll
    for (int r = 0; r < 8; r++) {
        int bs = w * 8 + r;
        float v0 = y0[bs * 256 + lane], v1 = y0[bs * 256 + lane + 64];
        float v2 = y0[bs * 256 + lane + 128], v3 = y0[bs * 256 + lane + 192];
        float s = v0 + v1 + v2 + v3;
        float s2 = v0 * v0 + v1 * v1 + v2 * v2 + v3 * v3;
        #pragma unroll
        for (int off = 32; off > 0; off >>= 1) { s += __shfl_xor(s, off); s2 += __shfl_xor(s2, off); }
        if (lane == 0) {
            float mean = s * (1.f / 256.f);
            float var = s2 * (1.f / 256.f) - mean * mean;
            mstat[bs][0] = mean;
            mstat[bs][1] = rsqrtf(var + 1e-5f);
        }
    }
    __syncthreads();
    float gk = lng[tid], bk = lnb[tid];
    #pragma unroll 4
    for (int i = 0; i < 32; i++)
        y0[i * 256 + tid] = (y0[i * 256 + tid] - mstat[i][0]) * mstat[i][1] * gk + bk;
    __syncthreads();
    int c = blockIdx.x * 4 + w;
    const float* wr = w1t + (size_t)c * 256;
    float wf0 = wr[lane], wf1 = wr[lane + 64], wf2 = wr[lane + 128], wf3 = wr[lane + 192];
    float bb = b1[c];
    for (int bs = 0; bs < 32; bs++) {
        const float* x = &y0[bs * 256];
        float s = x[lane] * wf0 + x[lane + 64] * wf1 + x[lane + 128] * wf2 + x[lane + 192] * wf3;
        #pragma unroll
        for (int off = 32; off > 0; off >>= 1) s += __shfl_xor(s, off);
        if (lane == 0) t1[bs * 1024 + c] = fmaxf(s + bb, 0.f);
    }
}

// k_mlp22: slots = h + t1@w2 + b2. grid 128 x 256 (2 cols x 2 k-halves per block).
__global__ __launch_bounds__(256) void k_mlp22(
    const float* __restrict__ t1, const float* __restrict__ hbuf,
    const float* __restrict__ w2t, const float* __restrict__ b2, float* __restrict__ slots)
{
    int tid = threadIdx.x, lane = tid & 63, w = tid >> 6;
    int ci = w & 1, half = w >> 1;
    int c = blockIdx.x * 2 + ci;
    __shared__ float part[2][2][32];
    const float* wr = w2t + (size_t)c * 1024 + half * 512;
    float wf[8];
    #pragma unroll
    for (int i = 0; i < 8; i++) wf[i] = wr[lane + 64 * i];
    for (int bs = 0; bs < 32; bs++) {
        const float* x = t1 + bs * 1024 + half * 512;
        float s = 0.f;
        #pragma unroll
        for (int i = 0; i < 8; i++) s += x[lane + 64 * i] * wf[i];
        #pragma unroll
        for (int off = 32; off > 0; off >>= 1) s += __shfl_xor(s, off);
        if (lane == 0) part[ci][half][bs] = s;
    }
    __syncthreads();
    if (tid < 64) {
        int bs = tid & 31, cc = blockIdx.x * 2 + (tid >> 5);
        slots[bs * 256 + cc] = hbuf[bs * 256 + cc] + b2[cc]
                             + part[tid >> 5][0][bs] + part[tid >> 5][1][bs];
    }
}

// ---------------- final: attn normalize + out = slots@fin_w + fin_b ----------------
__global__ __launch_bounds__(256) void final_k(
    const float* __restrict__ attn_raw, const float* __restrict__ denom,
    const float* __restrict__ slots, const float* __restrict__ fin_w,
    const float* __restrict__ fin_b, float* __restrict__ out_attn, float* __restrict__ out_slots)
{
    int blk = blockIdx.x, tid = threadIdx.x;
    if (blk < 512) {
        int b = blk >> 7;
        int idx = (blk & 127) * 256 + tid;
        int s = idx >> 12;
        out_attn[(size_t)b * Sc * Nc_ + idx] = attn_raw[(size_t)b * Sc * Nc_ + idx] / denom[b * 8 + s];
    } else {
        int bs = blk - 512;
        __shared__ float sl[256];
        sl[tid] = slots[bs * 256 + tid];
        __syncthreads();
        float acc = fin_b[tid];
        for (int j = 0; j < 256; j++) acc += sl[j] * fin_w[j * 256 + tid];
        out_slots[bs * 256 + tid] = acc;
    }
}

extern "C" void kernel_launch(void* const* d_in, const int* in_sizes, int n_in,
                              void* d_out, int out_size, void* d_ws, size_t ws_size,
                              hipStream_t stream)
{
    const float* inputs       = (const float*)d_in[0];
    const float* point_coords = (const float*)d_in[1];
    const float* slots_param  = (const float*)d_in[2];
    const float* Sp0          = (const float*)d_in[3];
    const float* Ss0          = (const float*)d_in[4];
    const float* Qw           = (const float*)d_in[5];
    const float* Kw           = (const float*)d_in[6];
    const float* Vw           = (const float*)d_in[7];
    const float* norm_g       = (const float*)d_in[8];
    const float* norm_b       = (const float*)d_in[9];
    const float* gw           = (const float*)d_in[10];
    const float* gb           = (const float*)d_in[11];
    const float* fw1          = (const float*)d_in[12];
    const float* fb1          = (const float*)d_in[13];
    const float* fw2          = (const float*)d_in[14];
    const float* fb2          = (const float*)d_in[15];
    const float* gru_wi       = (const float*)d_in[16];
    const float* gru_wh       = (const float*)d_in[17];
    const float* gru_bi       = (const float*)d_in[18];
    const float* gru_bh       = (const float*)d_in[19];
    const float* mlp_ln_g     = (const float*)d_in[20];
    const float* mlp_ln_b     = (const float*)d_in[21];
    const float* mlp_w1       = (const float*)d_in[22];
    const float* mlp_b1       = (const float*)d_in[23];
    const float* mlp_w2       = (const float*)d_in[24];
    const float* mlp_b2       = (const float*)d_in[25];
    const float* im_ln1_g     = (const float*)d_in[26];
    const float* im_ln1_b     = (const float*)d_in[27];
    const float* im_w1        = (const float*)d_in[28];
    const float* im_b1        = (const float*)d_in[29];
    const float* im_w2        = (const float*)d_in[30];
    const float* im_b2        = (const float*)d_in[31];
    const float* im_ln2_g     = (const float*)d_in[32];
    const float* im_ln2_b     = (const float*)d_in[33];
    const float* fin_w        = (const float*)d_in[34];
    const float* fin_b        = (const float*)d_in[35];

    float* W = (float*)d_ws;
    u16*   AKVbf  = (u16*)(W);                  // 16384x512 bf16
    u16*   Abf    = (u16*)(W + 8388608);        // 16384x768 bf16
    u16*   h1bf   = (u16*)(W + 14680064);       // 16384x768 bf16
    u16*   x2bf   = (u16*)(W + 20971520);       // 16384x256 bf16
    float* KVF    = W + 23068672;               // 131072
    u16*   KVFbt  = (u16*)(W + 23199744);
    u16*   W1bt   = (u16*)(W + 23265280);
    u16*   W2bt   = (u16*)(W + 23560192);
    u16*   Qwbf   = (u16*)(W + 23658496);
    u16*   fw2bf  = (u16*)(W + 23691264);
    float* QF     = W + 23724032;               // 65536
    float* qv     = W + 23789568;               // 256
    float* G3     = W + 23789824;               // 768
    float* bias2  = W + 23790592;               // 512
    float* slots  = W + 23791104;               // 8192
    float* Spb    = W + 23799296;               // 96
    float* Ssb    = W + 23799392;               // 96
    float* w2q    = W + 23799488;               // 8192
    float* qcb    = W + 23807680;               // 32
    float* invv   = W + 23807712;               // 96
    float* attn_raw = W + 23807808;             // 131072
    float* denom  = W + 23938880;               // 32
    float* u1acc  = W + 23938912;               // 8192
    float* Spacc  = W + 23947104;               // 96
    float* Epacc  = W + 23947200;               // 96
    float* updb   = W + 23947296;               // 8192
    float* hbuf   = W + 23955488;               // 8192
    float* t1buf  = W + 23963680;               // 32768
    float* fw2t   = W + 23996448;               // 65536
    float* wit    = W + 24061984;               // 196608
    float* wht    = W + 24258592;               // 196608
    float* w1t    = W + 24455200;               // 262144
    float* w2t    = W + 24717344;               // 262144  -- end ~24,979,488 f (~100 MB)

    // ---- one-time precompute ----
    prep_k<<<530, 512, 0, stream>>>(Kw, Vw, fw1, gw, gb, fb1, Qw, fb2, fw2,
                                    slots_param, Sp0, Ss0,
                                    KVF, G3, bias2, qv, slots, Spb, Ssb, Qwbf, fw2bf);
    tcvt3_k<<<dim3(24, 24, 3), 256, 0, stream>>>(im_w1, W1bt, im_w2, W2bt, KVF, KVFbt);
    tcvtf_k<<<dim3(32, 32, 5), 256, 0, stream>>>(fw2, fw2t, gru_wi, wit, gru_wh, wht,
                                                 mlp_w1, w1t, mlp_w2, w2t);
    mfma_gemm<false, false><<<dim3(2, 2), 256, 0, stream>>>(Qwbf, fw2bf, nullptr, QF, 256, 256, 256);

    // ---- input MLP (bf16 MFMA) ----
    lncvt_k<<<16384, 256, 0, stream>>>(inputs, im_ln1_g, im_ln1_b, Abf, DINc);
    mfma_gemm<true, true><<<dim3(6, 128), 256, 0, stream>>>(Abf, W1bt, im_b1, h1bf, 16384, 768, 768);
    mfma_gemm<false, true><<<dim3(2, 128), 256, 0, stream>>>(h1bf, W2bt, im_b2, x2bf, 16384, 256, 768);
    lncvt_bf_k<<<16384, 256, 0, stream>>>(x2bf, im_ln2_g, im_ln2_b);
    mfma_gemm<false, true><<<dim3(4, 128), 256, 0, stream>>>(x2bf, KVFbt, bias2, AKVbf, 16384, 512, 256);

    float* out_slots = (float*)d_out;
    float* out_attn  = (float*)d_out + Bc * Sc * Dc;

    // ---- iteration loop ----
    qprep2_k<<<32, 256, 0, stream>>>(slots, norm_g, norm_b, QF, qv, Ssb,
                                     w2q, qcb, invv, denom, u1acc, Spacc, Epacc);
    for (int t = 0; t < 3; t++) {
        fused_iter_k<false><<<dim3(128, 4), 512, 0, stream>>>(
            AKVbf, point_coords, G3, w2q, qcb, Spb, invv,
            denom, u1acc, Spacc, Epacc, nullptr);
        k_upd2<<<64, 256, 0, stream>>>(u1acc, denom, fw2t, fb2, Spacc, Epacc, updb, Spb, Ssb);
        k_gates2<<<256, 384, 0, stream>>>(updb, slots, wit, wht, gru_bi, gru_bh, hbuf);
        k_mlp12<<<256, 256, 0, stream>>>(hbuf, mlp_ln_g, mlp_ln_b, w1t, mlp_b1, t1buf);
        k_mlp22<<<128, 256, 0, stream>>>(t1buf, hbuf, w2t, mlp_b2, slots);
        qprep2_k<<<32, 256, 0, stream>>>(slots, norm_g, norm_b, QF, qv, Ssb,
                                         w2q, qcb, invv, denom, u1acc, Spacc, Epacc);
    }
    fused_iter_k<true><<<dim3(128, 4), 512, 0, stream>>>(
        AKVbf, point_coords, G3, w2q, qcb, Spb, invv,
        denom, u1acc, Spacc, Epacc, attn_raw);
    final_k<<<544, 256, 0, stream>>>(attn_raw, denom, slots, fin_w, fin_b,
                                     out_attn, out_slots);
}

// Round 10
// 528.573 us; speedup vs baseline: 1.1485x; 1.1485x over previous
//
#include <hip/hip_runtime.h>
#include <math.h>

typedef unsigned short u16;
typedef short short8 __attribute__((ext_vector_type(8)));
typedef float f32x4 __attribute__((ext_vector_type(4)));

#define Bc 4
#define Nc_ 4096
#define DINc 768
#define Dc 256
#define Sc 8
#define SCALEc 0.0625f
#define EPSc 1e-8f

__device__ __forceinline__ u16 f2bf(float f) {
    union { float f; unsigned u; } x; x.f = f;
    unsigned r = x.u + 0x7fffu + ((x.u >> 16) & 1u);
    return (u16)(r >> 16);
}
__device__ __forceinline__ float bf2f(u16 v) {
    union { unsigned u; float f; } x; x.u = ((unsigned)v) << 16; return x.f;
}
__device__ __forceinline__ float rfl(float x) {
    return __int_as_float(__builtin_amdgcn_readfirstlane(__float_as_int(x)));
}

#define GLDS(g, l) __builtin_amdgcn_global_load_lds( \
    (const __attribute__((address_space(1))) void*)(g), \
    (__attribute__((address_space(3))) void*)(l), 16, 0, 0)

// ================= bf16 MFMA GEMM: C[M][N] = A[M][K] @ Bt[N][K]^T + bias ================
// XCD-bijective block swizzle (m204): each XCD owns a contiguous by-range so A row-panels
// stay resident in that XCD's L2.
template<bool RELU, bool BF16OUT>
__global__ __launch_bounds__(256) void mfma_gemm(
    const u16* __restrict__ A, const u16* __restrict__ Bt,
    const float* __restrict__ bias, void* __restrict__ Cv,
    int M, int N, int K)
{
    __shared__ u16 lA[128 * 32];
    __shared__ u16 lB[128 * 32];
    const int tid = threadIdx.x;
    const int lane = tid & 63, w = tid >> 6;
    const int wm = w >> 1, wn = w & 1;

    const int nwg = gridDim.x * gridDim.y;
    int orig = blockIdx.y * gridDim.x + blockIdx.x;
    int q = nwg >> 3, r = nwg & 7;
    int xcd = orig & 7, loc = orig >> 3;
    int wgid = (xcd < r ? xcd * (q + 1) : r * (q + 1) + (xcd - r) * q) + loc;
    const int m0 = (wgid / gridDim.x) * 128, n0 = (wgid % gridDim.x) * 128;

    f32x4 acc[4][4];
    #pragma unroll
    for (int mi = 0; mi < 4; mi++)
        #pragma unroll
        for (int ni = 0; ni < 4; ni++)
            #pragma unroll
            for (int r2 = 0; r2 < 4; r2++) acc[mi][ni][r2] = 0.f;

    const int arow = (w << 5) + (lane >> 2);
    const int kc_s = (((lane & 3) ^ ((arow >> 1) & 3)) << 3);
    const size_t K16 = (size_t)K << 4;
    const u16* ga = A + (size_t)(m0 + arow) * K + kc_s;
    const u16* gb = Bt + (size_t)(n0 + arow) * K + kc_s;
    u16* la0 = &lA[w << 10];
    u16* la1 = &lA[(w << 10) + 512];
    u16* lb0 = &lB[w << 10];
    u16* lb1 = &lB[(w << 10) + 512];

    for (int k0 = 0; k0 < K; k0 += 32) {
        GLDS(ga + k0, la0);
        GLDS(ga + k0 + K16, la1);
        GLDS(gb + k0, lb0);
        GLDS(gb + k0 + K16, lb1);
        asm volatile("s_waitcnt vmcnt(0)" ::: "memory");
        __syncthreads();
        short8 af[4], bf[4];
        #pragma unroll
        for (int mi = 0; mi < 4; mi++) {
            int row = (wm << 6) + (mi << 4) + (lane & 15);
            int koff = (((lane >> 4) ^ ((row >> 1) & 3)) << 3);
            af[mi] = *(const short8*)&lA[row * 32 + koff];
        }
        #pragma unroll
        for (int ni = 0; ni < 4; ni++) {
            int row = (wn << 6) + (ni << 4) + (lane & 15);
            int koff = (((lane >> 4) ^ ((row >> 1) & 3)) << 3);
            bf[ni] = *(const short8*)&lB[row * 32 + koff];
        }
        #pragma unroll
        for (int mi = 0; mi < 4; mi++)
            #pragma unroll
            for (int ni = 0; ni < 4; ni++)
                acc[mi][ni] = __builtin_amdgcn_mfma_f32_16x16x32_bf16(af[mi], bf[ni], acc[mi][ni], 0, 0, 0);
        __syncthreads();
    }

    const int ccol = lane & 15;
    const int crow = (lane >> 4) << 2;
    #pragma unroll
    for (int mi = 0; mi < 4; mi++) {
        #pragma unroll
        for (int ni = 0; ni < 4; ni++) {
            int colg = n0 + (wn << 6) + (ni << 4) + ccol;
            float bv = bias ? bias[colg] : 0.f;
            #pragma unroll
            for (int r2 = 0; r2 < 4; r2++) {
                int rowg = m0 + (wm << 6) + (mi << 4) + crow + r2;
                float v = acc[mi][ni][r2] + bv;
                if (RELU) v = fmaxf(v, 0.f);
                if (BF16OUT) ((u16*)Cv)[(size_t)rowg * N + colg] = f2bf(v);
                else         ((float*)Cv)[(size_t)rowg * N + colg] = v;
            }
        }
    }
}

// ============== row-LayerNorm + bf16 convert, f32 input (K<=768) ==============
__global__ __launch_bounds__(256) void lncvt_k(
    const float* __restrict__ X, const float* __restrict__ g, const float* __restrict__ b,
    u16* __restrict__ out, int K)
{
    int row = blockIdx.x, tid = threadIdx.x, lane = tid & 63, wave = tid >> 6;
    __shared__ float buf[768];
    __shared__ float rs[4], rs2[4];
    float s = 0.f, s2 = 0.f;
    for (int k = tid; k < K; k += 256) {
        float v = X[(size_t)row * K + k];
        buf[k] = v; s += v; s2 += v * v;
    }
    #pragma unroll
    for (int off = 32; off > 0; off >>= 1) { s += __shfl_xor(s, off); s2 += __shfl_xor(s2, off); }
    if (lane == 0) { rs[wave] = s; rs2[wave] = s2; }
    __syncthreads();
    float inv = 1.f / (float)K;
    float mean = (rs[0] + rs[1] + rs[2] + rs[3]) * inv;
    float m2 = (rs2[0] + rs2[1] + rs2[2] + rs2[3]) * inv;
    float rstd = rsqrtf(m2 - mean * mean + 1e-5f);
    for (int k = tid; k < K; k += 256)
        out[(size_t)row * K + k] = f2bf((buf[k] - mean) * rstd * g[k] + b[k]);
}

// ============== row-LayerNorm in-place on bf16 (K==256) ==============
__global__ __launch_bounds__(256) void lncvt_bf_k(
    u16* __restrict__ X, const float* __restrict__ g, const float* __restrict__ b)
{
    int row = blockIdx.x, tid = threadIdx.x, lane = tid & 63, wave = tid >> 6;
    __shared__ float rs[4], rs2[4];
    float v = bf2f(X[(size_t)row * 256 + tid]);
    float s = v, s2 = v * v;
    #pragma unroll
    for (int off = 32; off > 0; off >>= 1) { s += __shfl_xor(s, off); s2 += __shfl_xor(s2, off); }
    if (lane == 0) { rs[wave] = s; rs2[wave] = s2; }
    __syncthreads();
    float mean = (rs[0] + rs[1] + rs[2] + rs[3]) * (1.f / 256.f);
    float m2 = (rs2[0] + rs2[1] + rs2[2] + rs2[3]) * (1.f / 256.f);
    float rstd = rsqrtf(m2 - mean * mean + 1e-5f);
    X[(size_t)row * 256 + tid] = f2bf((v - mean) * rstd * g[tid] + b[tid]);
}

// ============== merged 3-way transpose+convert (f32 -> bf16 transposed) ==============
__global__ __launch_bounds__(256) void tcvt3_k(
    const float* __restrict__ in0, u16* __restrict__ out0,
    const float* __restrict__ in1, u16* __restrict__ out1,
    const float* __restrict__ in2, u16* __restrict__ out2)
{
    int z = blockIdx.z;
    const float* in; u16* out; int R, C;
    if (z == 0) { in = in0; out = out0; R = 768; C = 768; }
    else if (z == 1) { in = in1; out = out1; R = 768; C = 256; }
    else { in = in2; out = out2; R = 256; C = 512; }
    int r0 = blockIdx.y * 32, c0 = blockIdx.x * 32;
    if (r0 >= R || c0 >= C) return;
    __shared__ float tile[32][33];
    int tx = threadIdx.x & 31, ty = threadIdx.x >> 5;
    #pragma unroll
    for (int i = 0; i < 32; i += 8)
        tile[ty + i][tx] = in[(size_t)(r0 + ty + i) * C + c0 + tx];
    __syncthreads();
    #pragma unroll
    for (int i = 0; i < 32; i += 8)
        out[(size_t)(c0 + ty + i) * R + r0 + tx] = f2bf(tile[tx][ty + i]);
}

// ============ merged one-time precompute (+ FWI = fw2@gru_wi, biasI = fb2@gru_wi+gbi) ====
__global__ __launch_bounds__(512) void prep_k(
    const float* __restrict__ Kw, const float* __restrict__ Vw, const float* __restrict__ fw1,
    const float* __restrict__ gw, const float* __restrict__ gb, const float* __restrict__ fb1,
    const float* __restrict__ Qw, const float* __restrict__ fb2, const float* __restrict__ fw2,
    const float* __restrict__ slots_param, const float* __restrict__ Sp0, const float* __restrict__ Ss0,
    const float* __restrict__ gwi, const float* __restrict__ gbi,
    float* __restrict__ KVF, float* __restrict__ G3, float* __restrict__ bias2,
    float* __restrict__ qv, float* __restrict__ slots, float* __restrict__ Spb, float* __restrict__ Ssb,
    u16* __restrict__ Qwbf, u16* __restrict__ fw2bf,
    float* __restrict__ FWI, float* __restrict__ biasI)
{
    int blk = blockIdx.x, tid = threadIdx.x;
    if (blk < 256) {                                     // KVF
        int k = blk, j = tid;
        const float* Mrow = (j < 256 ? Kw : Vw) + k * 256;
        int jj = j & 255;
        float acc = 0.f;
        for (int d = 0; d < 256; d++) acc += Mrow[d] * fw1[d * 256 + jj];
        KVF[k * 512 + j] = acc;
    } else if (blk == 256) {                             // G3, bias2
        if (tid < 256) {
            int j = tid;
            float g0 = 0, g1 = 0, g2 = 0, bb = 0;
            for (int d = 0; d < 256; d++) {
                float f = fw1[d * 256 + j];
                g0 += gw[d] * f; g1 += gw[256 + d] * f; g2 += gw[512 + d] * f;
                bb += gb[d] * f;
            }
            G3[j] = g0; G3[256 + j] = g1; G3[512 + j] = g2;
            float b1v = fb1[j] + bb;
            bias2[j] = b1v; bias2[256 + j] = b1v;
        }
    } else if (blk == 257) {                             // qv
        if (tid < 256) {
            float a = 0.f;
            for (int d = 0; d < 256; d++) a += Qw[tid * 256 + d] * fb2[d];
            qv[tid] = a;
        }
    } else if (blk < 274) {                              // init slots/Sp/Ss
        int idx = (blk - 258) * 512 + tid;
        slots[idx] = slots_param[idx & 2047];
        if (idx < Bc * Sc * 3) {
            int s3 = idx % 24;
            Spb[idx] = Sp0[s3];
            Ssb[idx] = Ss0[s3];
        }
    } else if (blk < 402) {                              // cvt Qw
        int i = (blk - 274) * 512 + tid;
        Qwbf[i] = f2bf(Qw[i]);
    } else if (blk < 530) {                              // cvt fw2
        int i = (blk - 402) * 512 + tid;
        fw2bf[i] = f2bf(fw2[i]);
    } else if (blk < 914) {                              // FWI[d][col] = sum_j fw2[d][j]*gwi[j][col]
        int idx = (blk - 530) * 512 + tid;
        int d = idx / 768, col = idx - d * 768;
        float a = 0.f;
        #pragma unroll 8
        for (int j = 0; j < 256; j++) a += fw2[d * 256 + j] * gwi[(size_t)j * 768 + col];
        FWI[idx] = a;
    } else {                                             // biasI[col] = gbi[col] + sum_j fb2[j]*gwi[j][col]
        int idx = (blk - 914) * 512 + tid;
        if (idx < 768) {
            float a = gbi[idx];
            #pragma unroll 8
            for (int j = 0; j < 256; j++) a += fb2[j] * gwi[(size_t)j * 768 + idx];
            biasI[idx] = a;
        }
    }
}

// ------- qprep: w2q = LN(slots)@QF ; qc ; invv ; zero accumulators for next iter -------
__global__ __launch_bounds__(256) void qprep2_k(
    const float* __restrict__ slots, const float* __restrict__ norm_g, const float* __restrict__ norm_b,
    const float* __restrict__ QF, const float* __restrict__ qv, const float* __restrict__ Ssb,
    float* __restrict__ w2q, float* __restrict__ qc, float* __restrict__ invv,
    float* __restrict__ denom, float* __restrict__ u1acc,
    float* __restrict__ Spacc, float* __restrict__ Epacc)
{
    int bs = blockIdx.x, tid = threadIdx.x, lane = tid & 63, wave = tid >> 6;
    __shared__ float sl[256];
    __shared__ float redS[4], redS2[4];
    u1acc[bs * 256 + tid] = 0.f;
    if (tid < 3) { Spacc[bs * 3 + tid] = 0.f; Epacc[bs * 3 + tid] = 0.f; }
    if (tid == 0) denom[bs] = 0.f;
    float v = slots[bs * 256 + tid];
    float s = v, s2 = v * v;
    #pragma unroll
    for (int off = 32; off > 0; off >>= 1) { s += __shfl_xor(s, off); s2 += __shfl_xor(s2, off); }
    if (lane == 0) { redS[wave] = s; redS2[wave] = s2; }
    __syncthreads();
    float mean = (redS[0] + redS[1] + redS[2] + redS[3]) * (1.f / 256.f);
    float m2 = (redS2[0] + redS2[1] + redS2[2] + redS2[3]) * (1.f / 256.f);
    float rstd = rsqrtf(m2 - mean * mean + 1e-5f);
    float slv = (v - mean) * rstd * norm_g[tid] + norm_b[tid];
    sl[tid] = slv;
    __syncthreads();
    float wq = 0.f;
    #pragma unroll 8
    for (int i = 0; i < 256; i++) wq += sl[i] * QF[i * 256 + tid];
    w2q[bs * 256 + tid] = wq;
    float c = slv * qv[tid];
    #pragma unroll
    for (int off = 32; off > 0; off >>= 1) c += __shfl_xor(c, off);
    __syncthreads();
    if (lane == 0) redS[wave] = c;
    __syncthreads();
    if (tid == 0) qc[bs] = redS[0] + redS[1] + redS[2] + redS[3];
    if (tid < 3) invv[bs * 3 + tid] = 1.f / (Ssb[bs * 3 + tid] * 5.0f + EPSc);
}

// ===== fused iteration: dots + softmax(s) + raw-weighted u1/moments/denom (bf16 AKV) ====
template<bool LAST>
__global__ __launch_bounds__(512, 2) void fused_iter_k(
    const u16* __restrict__ AKV, const float* __restrict__ P,
    const float* __restrict__ G3, const float* __restrict__ w2q,
    const float* __restrict__ qc, const float* __restrict__ Spb,
    const float* __restrict__ invv, float* __restrict__ denom,
    float* __restrict__ u1acc, float* __restrict__ Spacc, float* __restrict__ Epacc,
    float* __restrict__ attn_raw)
{
    const int b = blockIdx.y;
    const int tid = threadIdx.x, wave = tid >> 6, lane = tid & 63;
    __shared__ float uls[8][2048];
    __shared__ float dls[8][8];
    __shared__ float mls[8][8][6];

    const float4* G3f = (const float4*)G3;
    float4 g0 = G3f[lane], g1 = G3f[64 + lane], g2 = G3f[128 + lane];
    float4 wq[8];
    float sp0[8], sp1[8], sp2[8], iv0[8], iv1[8], iv2[8], qcr[8];
    #pragma unroll
    for (int s = 0; s < 8; s++) {
        wq[s] = ((const float4*)(w2q + (size_t)(b * 8 + s) * 256))[lane];
        sp0[s] = rfl(Spb[(b * 8 + s) * 3 + 0]);
        sp1[s] = rfl(Spb[(b * 8 + s) * 3 + 1]);
        sp2[s] = rfl(Spb[(b * 8 + s) * 3 + 2]);
        iv0[s] = rfl(invv[(b * 8 + s) * 3 + 0]);
        iv1[s] = rfl(invv[(b * 8 + s) * 3 + 1]);
        iv2[s] = rfl(invv[(b * 8 + s) * 3 + 2]);
        qcr[s] = rfl(qc[b * 8 + s]);
    }
    float4 au[8];
    #pragma unroll
    for (int s = 0; s < 8; s++) { au[s].x = 0.f; au[s].y = 0.f; au[s].z = 0.f; au[s].w = 0.f; }
    float den[8] = {0.f, 0.f, 0.f, 0.f, 0.f, 0.f, 0.f, 0.f};
    float asp0 = 0.f, asp1 = 0.f, asp2 = 0.f, aep0 = 0.f, aep1 = 0.f, aep2 = 0.f;
    float attv = 0.f;

    const int n0 = blockIdx.x * 32 + wave * 4;
    for (int i = 0; i < 4; i++) {
        size_t base = (size_t)b * Nc_ + (n0 + i);
        ushort4 akr = ((const ushort4*)(AKV + base * 512))[lane];
        float4 ak;
        ak.x = bf2f(akr.x); ak.y = bf2f(akr.y); ak.z = bf2f(akr.z); ak.w = bf2f(akr.w);
        const float* pp = P + base * 3;
        float p0 = pp[0], p1 = pp[1], p2 = pp[2];
        float a[8];
        #pragma unroll
        for (int s = 0; s < 8; s++) {
            float r0 = (p0 - sp0[s]) * iv0[s];
            float r1 = (p1 - sp1[s]) * iv1[s];
            float r2 = (p2 - sp2[s]) * iv2[s];
            float d0;
            d0  = fmaxf(ak.x + r0 * g0.x + r1 * g1.x + r2 * g2.x, 0.f) * wq[s].x;
            d0 += fmaxf(ak.y + r0 * g0.y + r1 * g1.y + r2 * g2.y, 0.f) * wq[s].y;
            d0 += fmaxf(ak.z + r0 * g0.z + r1 * g1.z + r2 * g2.z, 0.f) * wq[s].z;
            d0 += fmaxf(ak.w + r0 * g0.w + r1 * g1.w + r2 * g2.w, 0.f) * wq[s].w;
            #pragma unroll
            for (int off = 32; off > 0; off >>= 1) d0 += __shfl_xor(d0, off);
            a[s] = (d0 + qcr[s]) * SCALEc;
        }
        float mx = a[0];
        #pragma unroll
        for (int s = 1; s < 8; s++) mx = fmaxf(mx, a[s]);
        float sum = 0.f;
        #pragma unroll
        for (int s = 0; s < 8; s++) { a[s] = __expf(a[s] - mx); sum += a[s]; }
        float inv = 1.f / sum;
        #pragma unroll
        for (int s = 0; s < 8; s++) { a[s] = a[s] * inv + EPSc; den[s] += a[s]; }
        if (LAST) {
            #pragma unroll
            for (int s = 0; s < 8; s++)
                if (lane < 32 && (lane & 3) == i && (lane >> 2) == s) attv = a[s];
        } else {
            ushort4 avr = ((const ushort4*)(AKV + base * 512 + 256))[lane];
            float4 av;
            av.x = bf2f(avr.x); av.y = bf2f(avr.y); av.z = bf2f(avr.z); av.w = bf2f(avr.w);
            #pragma unroll
            for (int s = 0; s < 8; s++) {
                float r0 = (p0 - sp0[s]) * iv0[s];
                float r1 = (p1 - sp1[s]) * iv1[s];
                float r2 = (p2 - sp2[s]) * iv2[s];
                float as = a[s];
                au[s].x += as * fmaxf(av.x + r0 * g0.x + r1 * g1.x + r2 * g2.x, 0.f);
                au[s].y += as * fmaxf(av.y + r0 * g0.y + r1 * g1.y + r2 * g2.y, 0.f);
                au[s].z += as * fmaxf(av.z + r0 * g0.z + r1 * g1.z + r2 * g2.z, 0.f);
                au[s].w += as * fmaxf(av.w + r0 * g0.w + r1 * g1.w + r2 * g2.w, 0.f);
            }
            if (lane < 8) {
                float as = a[lane];
                asp0 += as * p0; asp1 += as * p1; asp2 += as * p2;
                aep0 += as * p0 * p0; aep1 += as * p1 * p1; aep2 += as * p2 * p2;
            }
        }
    }
    if (!LAST) {
        #pragma unroll
        for (int s = 0; s < 8; s++)
            *(float4*)&uls[wave][s * 256 + lane * 4] = au[s];
        if (lane < 8) {
            mls[wave][lane][0] = asp0; mls[wave][lane][1] = asp1; mls[wave][lane][2] = asp2;
            mls[wave][lane][3] = aep0; mls[wave][lane][4] = aep1; mls[wave][lane][5] = aep2;
        }
    }
    if (lane == 0) {
        #pragma unroll
        for (int s = 0; s < 8; s++) dls[wave][s] = den[s];
    }
    __syncthreads();
    if (!LAST) {
        for (int idx = tid; idx < 2048; idx += 512) {
            float v = 0.f;
            #pragma unroll
            for (int w2 = 0; w2 < 8; w2++) v += uls[w2][idx];
            atomicAdd(&u1acc[b * 2048 + idx], v);
        }
        if (tid < 48) {
            int s = tid / 6, c = tid % 6;
            float v = 0.f;
            #pragma unroll
            for (int w2 = 0; w2 < 8; w2++) v += mls[w2][s][c];
            if (c < 3) atomicAdd(&Spacc[b * 24 + s * 3 + c], v);
            else       atomicAdd(&Epacc[b * 24 + s * 3 + (c - 3)], v);
        }
    }
    if (tid < 8) {
        float v = 0.f;
        #pragma unroll
        for (int w2 = 0; w2 < 8; w2++) v += dls[w2][tid];
        atomicAdd(&denom[b * 8 + tid], v);
    }
    if (LAST && lane < 32) {
        attn_raw[(size_t)(b * 8 + (lane >> 2)) * Nc_ + n0 + (lane & 3)] = attv;
    }
}

// ---- k_gates_f: GRU gates directly from u1 via folded FWI ; Sp/Ss finalize ; -> h ----
// grid (32, 8) x 256thr  — round-6-proven structure, k_upd eliminated algebraically.
__global__ __launch_bounds__(256) void k_gates_f(
    const float* __restrict__ u1acc, const float* __restrict__ denom,
    const float* __restrict__ slots,
    const float* __restrict__ FWI, const float* __restrict__ gwh,
    const float* __restrict__ biasI, const float* __restrict__ gbh,
    const float* __restrict__ Spacc, const float* __restrict__ Epacc,
    float* __restrict__ hbuf, float* __restrict__ Spb, float* __restrict__ Ssb)
{
    int bs = blockIdx.x, chunk = blockIdx.y;
    int tid = threadIdx.x, c = tid & 31, ks = tid >> 5;
    __shared__ float u[256], sp[256];
    __shared__ float part[6][8][33];
    float idn = 1.f / denom[bs];
    u[tid] = u1acc[bs * 256 + tid] * idn;
    sp[tid] = slots[bs * 256 + tid];
    if (chunk == 0 && tid < 3) {
        float spv = Spacc[bs * 3 + tid] * idn;
        float ep  = Epacc[bs * 3 + tid] * idn;
        Spb[bs * 3 + tid] = spv;
        Ssb[bs * 3 + tid] = sqrtf(fmaxf(ep - spv * spv, 0.f) + EPSc);
    }
    __syncthreads();
    int col = (chunk << 5) + c;
    float a0 = 0, a1 = 0, a2 = 0, h0 = 0, h1 = 0, h2 = 0;
    int j0 = ks << 5;
    for (int j = j0; j < j0 + 32; j++) {
        const float* wi = FWI + (size_t)j * 768;
        const float* wh = gwh + (size_t)j * 768;
        float uj = u[j], sj = sp[j];
        a0 += uj * wi[col]; a1 += uj * wi[col + 256]; a2 += uj * wi[col + 512];
        h0 += sj * wh[col]; h1 += sj * wh[col + 256]; h2 += sj * wh[col + 512];
    }
    part[0][ks][c] = a0; part[1][ks][c] = a1; part[2][ks][c] = a2;
    part[3][ks][c] = h0; part[4][ks][c] = h1; part[5][ks][c] = h2;
    __syncthreads();
    if (tid < 32) {
        int col2 = (chunk << 5) + tid;
        float gx0 = biasI[col2], gx1 = biasI[col2 + 256], gx2 = biasI[col2 + 512];
        float gh0 = gbh[col2], gh1 = gbh[col2 + 256], gh2 = gbh[col2 + 512];
        #pragma unroll
        for (int r = 0; r < 8; r++) {
            gx0 += part[0][r][tid]; gx1 += part[1][r][tid]; gx2 += part[2][r][tid];
            gh0 += part[3][r][tid]; gh1 += part[4][r][tid]; gh2 += part[5][r][tid];
        }
        float rg = 1.f / (1.f + expf(-(gx0 + gh0)));
        float zg = 1.f / (1.f + expf(-(gx1 + gh1)));
        float ng = tanhf(gx2 + rg * gh2);
        hbuf[bs * 256 + col2] = (1.f - zg) * ng + zg * sp[col2];
    }
}

// ---------------- mlp1: t1 = relu(LN(h)@w1 + b1)  (round-6 proven) ----------------
__global__ __launch_bounds__(256) void k_mlp1(
    const float* __restrict__ hbuf, const float* __restrict__ lng, const float* __restrict__ lnb,
    const float* __restrict__ w1, const float* __restrict__ b1, float* __restrict__ t1)
{
    int bs = blockIdx.x, chunk = blockIdx.y;
    int tid = threadIdx.x, lane = tid & 63, wave = tid >> 6;
    int c = tid & 31, ks = tid >> 5;
    __shared__ float y0[256];
    __shared__ float part[8][33];
    __shared__ float rs[4], rs2[4];
    float h = hbuf[bs * 256 + tid];
    float s = h, s2 = h * h;
    #pragma unroll
    for (int off = 32; off > 0; off >>= 1) { s += __shfl_xor(s, off); s2 += __shfl_xor(s2, off); }
    if (lane == 0) { rs[wave] = s; rs2[wave] = s2; }
    __syncthreads();
    float mean = (rs[0] + rs[1] + rs[2] + rs[3]) * (1.f / 256.f);
    float m2 = (rs2[0] + rs2[1] + rs2[2] + rs2[3]) * (1.f / 256.f);
    float rstd = rsqrtf(m2 - mean * mean + 1e-5f);
    y0[tid] = (h - mean) * rstd * lng[tid] + lnb[tid];
    __syncthreads();
    int col = (chunk << 5) + c;
    float p = 0.f;
    int j0 = ks << 5;
    for (int j = j0; j < j0 + 32; j++) p += y0[j] * w1[(size_t)j * 1024 + col];
    part[ks][c] = p;
    __syncthreads();
    if (tid < 32) {
        int col2 = (chunk << 5) + tid;
        float a = b1[col2];
        #pragma unroll
        for (int r = 0; r < 8; r++) a += part[r][tid];
        t1[bs * 1024 + col2] = fmaxf(a, 0.f);
    }
}

// ---------------- mlp2: slots = h + t1@w2 + b2  (round-6 proven) ----------------
__global__ __launch_bounds__(256) void k_mlp2(
    const float* __restrict__ t1, const float* __restrict__ hbuf,
    const float* __restrict__ w2, const float* __restrict__ b2, float* __restrict__ slots)
{
    int bs = blockIdx.x, chunk = blockIdx.y;
    int tid = threadIdx.x, c = tid & 31, ks = tid >> 5;
    __shared__ float t1s[1024];
    __shared__ float part[8][33];
    for (int i = tid; i < 1024; i += 256) t1s[i] = t1[bs * 1024 + i];
    __syncthreads();
    int col = (chunk << 5) + c;
    float p = 0.f;
    int j0 = ks << 7;
    for (int j = j0; j < j0 + 128; j++) p += t1s[j] * w2[(size_t)j * 256 + col];
    part[ks][c] = p;
    __syncthreads();
    if (tid < 32) {
        int col2 = (chunk << 5) + tid;
        float a = b2[col2] + hbuf[bs * 256 + col2];
        #pragma unroll
        for (int r = 0; r < 8; r++) a += part[r][tid];
        slots[bs * 256 + col2] = a;
    }
}

// ---------------- final: attn normalize + out = slots@fin_w + fin_b ----------------
__global__ __launch_bounds__(256) void final_k(
    const float* __restrict__ attn_raw, const float* __restrict__ denom,
    const float* __restrict__ slots, const float* __restrict__ fin_w,
    const float* __restrict__ fin_b, float* __restrict__ out_attn, float* __restrict__ out_slots)
{
    int blk = blockIdx.x, tid = threadIdx.x;
    if (blk < 512) {
        int b = blk >> 7;
        int idx = (blk & 127) * 256 + tid;
        int s = idx >> 12;
        out_attn[(size_t)b * Sc * Nc_ + idx] = attn_raw[(size_t)b * Sc * Nc_ + idx] / denom[b * 8 + s];
    } else {
        int bs = blk - 512;
        __shared__ float sl[256];
        sl[tid] = slots[bs * 256 + tid];
        __syncthreads();
        float acc = fin_b[tid];
        for (int j = 0; j < 256; j++) acc += sl[j] * fin_w[j * 256 + tid];
        out_slots[bs * 256 + tid] = acc;
    }
}

extern "C" void kernel_launch(void* const* d_in, const int* in_sizes, int n_in,
                              void* d_out, int out_size, void* d_ws, size_t ws_size,
                              hipStream_t stream)
{
    const float* inputs       = (const float*)d_in[0];
    const float* point_coords = (const float*)d_in[1];
    const float* slots_param  = (const float*)d_in[2];
    const float* Sp0          = (const float*)d_in[3];
    const float* Ss0          = (const float*)d_in[4];
    const float* Qw           = (const float*)d_in[5];
    const float* Kw           = (const float*)d_in[6];
    const float* Vw           = (const float*)d_in[7];
    const float* norm_g       = (const float*)d_in[8];
    const float* norm_b       = (const float*)d_in[9];
    const float* gw           = (const float*)d_in[10];
    const float* gb           = (const float*)d_in[11];
    const float* fw1          = (const float*)d_in[12];
    const float* fb1          = (const float*)d_in[13];
    const float* fw2          = (const float*)d_in[14];
    const float* fb2          = (const float*)d_in[15];
    const float* gru_wi       = (const float*)d_in[16];
    const float* gru_wh       = (const float*)d_in[17];
    const float* gru_bi       = (const float*)d_in[18];
    const float* gru_bh       = (const float*)d_in[19];
    const float* mlp_ln_g     = (const float*)d_in[20];
    const float* mlp_ln_b     = (const float*)d_in[21];
    const float* mlp_w1       = (const float*)d_in[22];
    const float* mlp_b1       = (const float*)d_in[23];
    const float* mlp_w2       = (const float*)d_in[24];
    const float* mlp_b2       = (const float*)d_in[25];
    const float* im_ln1_g     = (const float*)d_in[26];
    const float* im_ln1_b     = (const float*)d_in[27];
    const float* im_w1        = (const float*)d_in[28];
    const float* im_b1        = (const float*)d_in[29];
    const float* im_w2        = (const float*)d_in[30];
    const float* im_b2        = (const float*)d_in[31];
    const float* im_ln2_g     = (const float*)d_in[32];
    const float* im_ln2_b     = (const float*)d_in[33];
    const float* fin_w        = (const float*)d_in[34];
    const float* fin_b        = (const float*)d_in[35];

    float* W = (float*)d_ws;
    u16*   AKVbf  = (u16*)(W);                  // 16384x512 bf16
    u16*   Abf    = (u16*)(W + 8388608);        // 16384x768 bf16
    u16*   h1bf   = (u16*)(W + 14680064);       // 16384x768 bf16
    u16*   x2bf   = (u16*)(W + 20971520);       // 16384x256 bf16
    float* KVF    = W + 23068672;               // 131072
    u16*   KVFbt  = (u16*)(W + 23199744);
    u16*   W1bt   = (u16*)(W + 23265280);
    u16*   W2bt   = (u16*)(W + 23560192);
    u16*   Qwbf   = (u16*)(W + 23658496);
    u16*   fw2bf  = (u16*)(W + 23691264);
    float* QF     = W + 23724032;               // 65536
    float* qv     = W + 23789568;               // 256
    float* G3     = W + 23789824;               // 768
    float* bias2  = W + 23790592;               // 512
    float* slots  = W + 23791104;               // 8192
    float* Spb    = W + 23799296;               // 96
    float* Ssb    = W + 23799392;               // 96
    float* w2q    = W + 23799488;               // 8192
    float* qcb    = W + 23807680;               // 32
    float* invv   = W + 23807712;               // 96
    float* attn_raw = W + 23807808;             // 131072
    float* denom  = W + 23938880;               // 32
    float* u1acc  = W + 23938912;               // 8192
    float* Spacc  = W + 23947104;               // 96
    float* Epacc  = W + 23947200;               // 96
    float* hbuf   = W + 23947296;               // 8192
    float* t1buf  = W + 23955488;               // 32768
    float* FWI    = W + 23988256;               // 196608
    float* biasI  = W + 24184864;               // 768   -- end ~24,185,632 f (~97 MB)

    // ---- one-time precompute (incl. FWI/biasI GRU-input folding) ----
    prep_k<<<916, 512, 0, stream>>>(Kw, Vw, fw1, gw, gb, fb1, Qw, fb2, fw2,
                                    slots_param, Sp0, Ss0, gru_wi, gru_bi,
                                    KVF, G3, bias2, qv, slots, Spb, Ssb, Qwbf, fw2bf,
                                    FWI, biasI);
    tcvt3_k<<<dim3(24, 24, 3), 256, 0, stream>>>(im_w1, W1bt, im_w2, W2bt, KVF, KVFbt);
    mfma_gemm<false, false><<<dim3(2, 2), 256, 0, stream>>>(Qwbf, fw2bf, nullptr, QF, 256, 256, 256);

    // ---- input MLP (bf16 MFMA, XCD-swizzled) ----
    lncvt_k<<<16384, 256, 0, stream>>>(inputs, im_ln1_g, im_ln1_b, Abf, DINc);
    mfma_gemm<true, true><<<dim3(6, 128), 256, 0, stream>>>(Abf, W1bt, im_b1, h1bf, 16384, 768, 768);
    mfma_gemm<false, true><<<dim3(2, 128), 256, 0, stream>>>(h1bf, W2bt, im_b2, x2bf, 16384, 256, 768);
    lncvt_bf_k<<<16384, 256, 0, stream>>>(x2bf, im_ln2_g, im_ln2_b);
    mfma_gemm<false, true><<<dim3(4, 128), 256, 0, stream>>>(x2bf, KVFbt, bias2, AKVbf, 16384, 512, 256);

    float* out_slots = (float*)d_out;
    float* out_attn  = (float*)d_out + Bc * Sc * Dc;

    // ---- iteration loop ----
    qprep2_k<<<32, 256, 0, stream>>>(slots, norm_g, norm_b, QF, qv, Ssb,
                                     w2q, qcb, invv, denom, u1acc, Spacc, Epacc);
    for (int t = 0; t < 3; t++) {
        fused_iter_k<false><<<dim3(128, 4), 512, 0, stream>>>(
            AKVbf, point_coords, G3, w2q, qcb, Spb, invv,
            denom, u1acc, Spacc, Epacc, nullptr);
        k_gates_f<<<dim3(32, 8), 256, 0, stream>>>(u1acc, denom, slots, FWI, gru_wh,
                                                   biasI, gru_bh, Spacc, Epacc,
                                                   hbuf, Spb, Ssb);
        k_mlp1<<<dim3(32, 32), 256, 0, stream>>>(hbuf, mlp_ln_g, mlp_ln_b, mlp_w1, mlp_b1, t1buf);
        k_mlp2<<<dim3(32, 8), 256, 0, stream>>>(t1buf, hbuf, mlp_w2, mlp_b2, slots);
        qprep2_k<<<32, 256, 0, stream>>>(slots, norm_g, norm_b, QF, qv, Ssb,
                                         w2q, qcb, invv, denom, u1acc, Spacc, Epacc);
    }
    fused_iter_k<true><<<dim3(128, 4), 512, 0, stream>>>(
        AKVbf, point_coords, G3, w2q, qcb, Spb, invv,
        denom, u1acc, Spacc, Epacc, attn_raw);
    final_k<<<544, 256, 0, stream>>>(attn_raw, denom, slots, fin_w, fin_b,
                                     out_attn, out_slots);
}